// Round 11
// baseline (199.992 us; speedup 1.0000x reference)
//
#include <hip/hip_runtime.h>
#include <stdint.h>

// VQ-VAE quantize forward, MI355X. Split-f16 MFMA distance GEMM.
// R14 (3rd submit; rounds 9/10 died to container-level infra failures —
// audit found no divergent barriers, no vmcnt deadlock, no LDS/global OOB,
// no overlay WAR: kernel sound). R13 mechanics retiled for cross-block
// overlap: BM=128, 4 waves x 32 rows, grid=512 = 2 independent blocks/CU
// (block A's phase-seam stalls — ds_read burst, vmcnt wait, argmin VALU,
// barrier skew — fill under block B's MFMA cluster; the single 8-wave
// block was lockstepped). Per-CU MFMA/LDS floors unchanged. A persistent
// in regs (128 VGPR, split once); prologue software-pipelined (X-scratch
// 2x32KB dbuf overlaying the B region, counted vmcnt(8)). K=64 phases,
// counted vmcnt(8) staging, raw s_barrier, setprio. s_en filled inside
// the prologue's final drain (keeps loop vmcnt exact). Distances
// bit-identical to R5..R13 (same split math, same hh/lh/hl order, same
// kc-ascending chain, same tie-breaks) -> same argmin/absmax.
// out = [values (BT*D)] [indexes as float (BT)] [loss (1)]

#define BT    65536     // 16*4096 rows
#define D     256       // codeword size
#define KCB   1024      // codebook size
#define BM    128       // rows per block tile (4 waves x 32 rows)
#define BN    128       // cols per phase
#define BK    32        // k sub-chunk (MFMA granularity)

typedef float    f32x4 __attribute__((ext_vector_type(4)));
typedef _Float16 f16x8 __attribute__((ext_vector_type(8)));

#define GLOAD_LDS16(g, l) \
  __builtin_amdgcn_global_load_lds((const __attribute__((address_space(1))) void*)(g), \
                                   (__attribute__((address_space(3))) void*)(l), 16, 0, 0)

// ---- split E -> Eh, El + fp32 |e|^2; also zeroes out_loss (1MB in; ~3us) ----
__global__ __launch_bounds__(256) void split_e_kernel(const float* __restrict__ E,
                                                      _Float16* __restrict__ Eh,
                                                      _Float16* __restrict__ El,
                                                      float* __restrict__ enorm,
                                                      float* __restrict__ out_loss) {
    if (blockIdx.x == 0 && threadIdx.x == 0) *out_loss = 0.f;
    const int r = blockIdx.x * 8 + (threadIdx.x >> 5);
    const size_t i0 = (size_t)r * D + (threadIdx.x & 31) * 8;
    float4 v0 = *(const float4*)(E + i0);
    float4 v1 = *(const float4*)(E + i0 + 4);
    float v[8] = {v0.x, v0.y, v0.z, v0.w, v1.x, v1.y, v1.z, v1.w};
    f16x8 h, l;
    float s = 0.f;
    #pragma unroll
    for (int j = 0; j < 8; ++j) {
        _Float16 hh = (_Float16)v[j];
        h[j] = hh;
        l[j] = (_Float16)(v[j] - (float)hh);
        s += v[j] * v[j];
    }
    *(f16x8*)(Eh + i0) = h;
    *(f16x8*)(El + i0) = l;
    #pragma unroll
    for (int off = 1; off < 32; off <<= 1) s += __shfl_xor(s, off, 64);
    if ((threadIdx.x & 31) == 0) enorm[r] = s;
}

// ---- main: A-in-register, K=64 phases, 2 blocks/CU, MFMA + argmin + loss
__global__ __launch_bounds__(256, 2) void vq_mfma_kernel(
    const float* __restrict__ X,
    const _Float16* __restrict__ Eh, const _Float16* __restrict__ El,
    const float* __restrict__ enorm, const float* __restrict__ E,
    float* __restrict__ out_vals, float* __restrict__ out_idx,
    float* __restrict__ out_loss) {
    // Bmem overlay: prologue = X scratch dbuf (2 x 32 rows x 256 f32; 1KB
    // rows of 64 16B chunks, phys chunk = c ^ (r&7), R11/R12-verified).
    // main loop = B buffers [buf][half][hl] of BN*BK f16 (64B rows, 4 slots,
    // phys slot = (c + (r>>1)) & 3, R5/R8-verified: 0 conflicts).
    __shared__ __align__(16) char Bmem[8 * BN * BK * 2];   // 64 KB
    __shared__ float s_en[KCB];                            // 4 KB
    __shared__ float s_bd[BM];                             // 512 B
    __shared__ int   s_bi[BM];                             // 512 B
    __shared__ float s_red[4];

    _Float16* const BB  = (_Float16*)Bmem;
    float*    const Xs0 = (float*)Bmem;
    float*    const Xs1 = (float*)(Bmem + 32 * 1024);

    const int tid  = threadIdx.x;
    const int w    = tid >> 6;        // wave 0..3 -> rows w*32..w*32+31
    const int lane = tid & 63;
    const int quad = lane >> 4;
    const int l16  = lane & 15;
    const int sxa  = l16 & 7;
    const int row0 = blockIdx.x * BM;

    // B staging lane constants (R11/R12 verbatim; linear LDS dest, swizzle
    // folded into the per-lane GLOBAL source address)
    const int sb_row = lane >> 2;                                 // row in 16-row chunk
    const int sb_off = ((((lane & 3) - (lane >> 3)) & 3) << 3);   // f16 offset
    // B frag-read physical slot (row bases are multiples of 16)
    const int kob = ((quad + ((l16 >> 1) & 3)) & 3) << 3;

    auto STAGE_PH = [&](int buf, int step) {   // step = nt*4 + q of TARGET phase
        const int col0 = (step >> 2) * BN;
        const int kb0  = (step & 3) * (2 * BK);
        #pragma unroll
        for (int h = 0; h < 2; ++h)
            #pragma unroll
            for (int t = 0; t < 2; ++t) {
                const int chunk = w * 2 + t;             // 0..7 (16 rows each)
                const int gr = col0 + chunk * 16 + sb_row;
                const size_t gb = (size_t)gr * D + kb0 + h * BK + sb_off;
                GLOAD_LDS16(Eh + gb, BB + (buf * 4 + h * 2 + 0) * (BN * BK) + chunk * 512);
                GLOAD_LDS16(El + gb, BB + (buf * 4 + h * 2 + 1) * (BN * BK) + chunk * 512);
            }
    };  // 8 loads per thread per call

    auto STAGE_X = [&](int buf, int p) {       // stage block rows p*32..p*32+31
        float* Xs = buf ? Xs1 : Xs0;
        #pragma unroll
        for (int rr = 0; rr < 8; ++rr) {
            const int sr = w * 8 + rr;                   // scratch row 0..31
            const int gr = row0 + p * 32 + sr;
            GLOAD_LDS16(X + (size_t)gr * D + ((lane ^ rr) << 2), &Xs[sr * D]);
        }
    };  // 8 loads per thread per call

    // ---- prologue: persist this wave's A slice (32 rows x 256 K) in regs;
    // pipelined across the 2x32KB scratch dbuf (counted vmcnt) ----
    f16x8 pah[2][8], pal[2][8];       // 128 VGPR
    float xs = 0.f;                   // sum of x^2 (each element exactly once)
    STAGE_X(0, 0);
    #pragma unroll
    for (int p = 0; p < 4; ++p) {
        if (p < 3) {
            STAGE_X((p + 1) & 1, p + 1);
            asm volatile("s_waitcnt vmcnt(8)" ::: "memory");   // pass p landed
        } else {
            asm volatile("s_waitcnt vmcnt(0)" ::: "memory");
            // fill s_en here: loads drain before the final barrier, keeping
            // the main loop's counted vmcnt exact.
            #pragma unroll
            for (int t = 0; t < 4; ++t) s_en[tid + t * 256] = enorm[tid + t * 256];
            asm volatile("s_waitcnt vmcnt(0) lgkmcnt(0)" ::: "memory");
        }
        __builtin_amdgcn_s_barrier();
        if (w == p) {                          // wave p consumes pass p
            const float* Xs = (p & 1) ? Xs1 : Xs0;
            #pragma unroll
            for (int i = 0; i < 2; ++i) {
                const float* rp = &Xs[(i * 16 + l16) * D];
                #pragma unroll
                for (int kc = 0; kc < 8; ++kc) {
                    const int c0 = kc * 8 + quad * 2;
                    const f32x4 v0 = *(const f32x4*)(rp + (((c0)     ^ sxa) << 2));
                    const f32x4 v1 = *(const f32x4*)(rp + (((c0 | 1) ^ sxa) << 2));
                    const float f[8] = {v0.x, v0.y, v0.z, v0.w, v1.x, v1.y, v1.z, v1.w};
                    #pragma unroll
                    for (int e = 0; e < 8; ++e) {
                        const _Float16 hh = (_Float16)f[e];
                        pah[i][kc][e] = hh;
                        pal[i][kc][e] = (_Float16)(f[e] - (float)hh);
                        xs += f[e] * f[e];
                    }
                }
            }
        }
        __builtin_amdgcn_s_barrier();   // pass consumed; buffer reusable
    }

    float rb_d[2][4];
    int   rb_i[2][4];
    #pragma unroll
    for (int i = 0; i < 2; ++i)
        #pragma unroll
        for (int r = 0; r < 4; ++r) { rb_d[i][r] = 3.4e38f; rb_i[i][r] = 0; }
    f32x4 acc[2][8];

    // ---- main loop: 8 nt x 4 phases; phase = K=64 (2 kc sub-steps).
    // q, sub unrolled -> pah index & buffer parity compile-time (rule #20).
    STAGE_PH(0, 0);
    for (int nt = 0; nt < 8; ++nt) {
        const int col0 = nt * BN;
        #pragma unroll
        for (int q = 0; q < 4; ++q) {
            const int cur = q & 1;
            if (nt == 7 && q == 3) {
                asm volatile("s_waitcnt vmcnt(0)" ::: "memory");
            } else {
                STAGE_PH(cur ^ 1, nt * 4 + q + 1);    // 8 loads in flight
                asm volatile("s_waitcnt vmcnt(8)" ::: "memory");  // prev phase landed
            }
            __builtin_amdgcn_s_barrier();             // cur valid block-wide

            if (q == 0) {
                #pragma unroll
                for (int i = 0; i < 2; ++i)
                    #pragma unroll
                    for (int j = 0; j < 8; ++j) acc[i][j] = (f32x4)0.0f;
            }

            #pragma unroll
            for (int sub = 0; sub < 2; ++sub) {
                const int kc = q * 2 + sub;           // compile-time
                const _Float16* Bh = BB + (cur * 4 + sub * 2 + 0) * (BN * BK);
                const _Float16* Bl = BB + (cur * 4 + sub * 2 + 1) * (BN * BK);
                __builtin_amdgcn_s_setprio(1);
                #pragma unroll
                for (int j = 0; j < 8; ++j) {
                    const int n = (j * 16 + l16) * BK + kob;
                    const f16x8 bh = *(const f16x8*)&Bh[n];
                    const f16x8 bl = *(const f16x8*)&Bl[n];
                    #pragma unroll
                    for (int i = 0; i < 2; ++i) {
                        acc[i][j] = __builtin_amdgcn_mfma_f32_16x16x32_f16(pah[i][kc], bh, acc[i][j], 0, 0, 0);
                        acc[i][j] = __builtin_amdgcn_mfma_f32_16x16x32_f16(pal[i][kc], bh, acc[i][j], 0, 0, 0);
                        acc[i][j] = __builtin_amdgcn_mfma_f32_16x16x32_f16(pah[i][kc], bl, acc[i][j], 0, 0, 0);
                    }
                }
                __builtin_amdgcn_s_setprio(0);
            }

            if (q == 3) {                 // nt complete: fold argmin
                #pragma unroll
                for (int j = 0; j < 8; ++j) {
                    const int c = col0 + j * 16 + l16;
                    const float en = s_en[c];
                    #pragma unroll
                    for (int i = 0; i < 2; ++i)
                        #pragma unroll
                        for (int r = 0; r < 4; ++r) {
                            const float sd = en - 2.0f * acc[i][j][r];
                            if (sd < rb_d[i][r]) { rb_d[i][r] = sd; rb_i[i][r] = c; }
                        }
                }
            }
            __builtin_amdgcn_s_barrier();  // all waves done reading cur
        }
    }

    // fold the 16 lanes of each quad (they partition this wave's cols);
    // each wave owns distinct rows -> no cross-wave merge needed
    #pragma unroll
    for (int off = 1; off < 16; off <<= 1) {
        #pragma unroll
        for (int i = 0; i < 2; ++i)
            #pragma unroll
            for (int r = 0; r < 4; ++r) {
                const float od = __shfl_xor(rb_d[i][r], off, 64);
                const int   oi = __shfl_xor(rb_i[i][r], off, 64);
                if (od < rb_d[i][r] || (od == rb_d[i][r] && oi < rb_i[i][r])) {
                    rb_d[i][r] = od; rb_i[i][r] = oi;
                }
            }
    }
    if (l16 == 0) {
        #pragma unroll
        for (int i = 0; i < 2; ++i)
            #pragma unroll
            for (int r = 0; r < 4; ++r) {
                const int m = w * 32 + i * 16 + quad * 4 + r;    // 0..127
                s_bd[m] = rb_d[i][r]; s_bi[m] = rb_i[i][r];
            }
    }
    __syncthreads();

    // epilogue: indexes + loss partial (sum|x|^2 + min dist), then gather
    float part = xs;
    if (tid < BM) {
        out_idx[row0 + tid] = (float)s_bi[tid];
        part += s_bd[tid];
    }

    #pragma unroll 4
    for (int r = 0; r < BM; ++r) {
        const int bi = s_bi[r];
        out_vals[(size_t)(row0 + r) * D + tid] = E[(size_t)bi * D + tid];
    }

    #pragma unroll
    for (int off = 1; off < 64; off <<= 1) part += __shfl_xor(part, off, 64);
    if (lane == 0) s_red[w] = part;
    __syncthreads();
    if (tid == 0) {
        const float tot = s_red[0] + s_red[1] + s_red[2] + s_red[3];
        atomicAdd(out_loss, tot * (1.1f / 16777216.f));  // loss1 + 0.1*loss2
    }
}

extern "C" void kernel_launch(void* const* d_in, const int* in_sizes, int n_in,
                              void* d_out, int out_size, void* d_ws, size_t ws_size,
                              hipStream_t stream) {
    const float* X = (const float*)d_in[0];
    const float* E = (const float*)d_in[1];
    float* out      = (float*)d_out;
    float* out_vals = out;
    float* out_idx  = out + (size_t)BT * D;
    float* out_loss = out + (size_t)BT * D + BT;

    char* ws = (char*)d_ws;
    _Float16* Eh    = (_Float16*)ws;
    _Float16* El    = Eh + (size_t)KCB * D;
    float*    enorm = (float*)(El + (size_t)KCB * D);
    (void)ws_size; (void)n_in; (void)in_sizes; (void)out_size;

    split_e_kernel<<<KCB / 8, 256, 0, stream>>>(E, Eh, El, enorm, out_loss);
    vq_mfma_kernel<<<BT / BM, 256, 0, stream>>>(X, Eh, El, enorm, E,
                                                out_vals, out_idx, out_loss);
}